// Round 9
// baseline (629.113 us; speedup 1.0000x reference)
//
#include <hip/hip_runtime.h>
#include <math.h>

#define N 256
#define Dd 128

__device__ __forceinline__ double inv2s2_of(int s){
    return (s==0)?0.5:(s==1)?5.0e-3:(s==2)?5.0e-5:5.0e-7;
}

// verified elementwise f64 GJ sweep of a 32x32 LDS tile.
// After the loop the swept tile = -D^{-1}; negate so P = D^{-1}.
__device__ __forceinline__ void sweep32(double P[32][33], int tid){
    if (tid < 64){
        int r = tid & 31, cg_ = tid >> 5;
        for (int j = 0; j < 32; j++){
            double d    = P[j][j];
            double invd = 1.0 / d;
            double cr   = P[r][j];
            double s    = cr * invd;
            bool rj = (r == j);
            double nv[16];
            #pragma unroll
            for (int c = 0; c < 16; c++){
                int col = cg_*16 + c;
                double pj = P[j][col];
                double v  = P[r][col];
                nv[c] = rj ? ((col == j) ? -invd : v * invd)
                           : ((col == j) ? s : v - s*pj);
            }
            #pragma unroll
            for (int c = 0; c < 16; c++) P[r][cg_*16+c] = nv[c];
        }
        #pragma unroll
        for (int c = 0; c < 16; c++) P[r][cg_*16+c] = -P[r][cg_*16+c];
    }
}

// ---------- 32x32 f64 LDS tile helpers (256 threads, 4 elems/thread) --------
__device__ __forceinline__ void ld_tile(double T[32][33], const double* __restrict__ G, int tid){
    __syncthreads();
    #pragma unroll
    for (int l=0;l<4;l++){ int e=tid+l*256; int r=e>>5,c=e&31; T[r][c]=G[(size_t)r*N+c]; }
    __syncthreads();
}
__device__ __forceinline__ void ld_pg(double T[32][33], const double* __restrict__ P, int tid){
    __syncthreads();
    #pragma unroll
    for (int l=0;l<4;l++){ int e=tid+l*256; T[e>>5][e&31]=P[e]; }
    __syncthreads();
}
__device__ __forceinline__ void st_tile(double* __restrict__ G, const double T[32][33], int tid){
    __syncthreads();
    #pragma unroll
    for (int l=0;l<4;l++){ int e=tid+l*256; int r=e>>5,c=e&31; G[(size_t)r*N+c]=T[r][c]; }
}
__device__ __forceinline__ void st_tileT(double* __restrict__ G, const double T[32][33], int tid){
    __syncthreads();
    #pragma unroll
    for (int l=0;l<4;l++){ int e=tid+l*256; int r=e>>5,c=e&31; G[(size_t)r*N+c]=T[c][r]; }
}
// D = A*B
__device__ __forceinline__ void mm_nn(double D[32][33], const double A[32][33],
                                      const double B[32][33], int tid){
    __syncthreads();
    double acc[4];
    #pragma unroll
    for (int l=0;l<4;l++){ int e=tid+l*256; int r=e>>5,c=e&31; double s=0.0;
        #pragma unroll
        for (int kk=0;kk<32;kk++) s += A[r][kk]*B[kk][c];
        acc[l]=s; }
    __syncthreads();
    #pragma unroll
    for (int l=0;l<4;l++){ int e=tid+l*256; D[e>>5][e&31]=acc[l]; }
    __syncthreads();
}
// D = G - A*B^T   (G global, ld=N)
__device__ __forceinline__ void mm_nt_subG(double D[32][33], const double* __restrict__ G,
                                           const double A[32][33], const double B[32][33], int tid){
    __syncthreads();
    double acc[4];
    #pragma unroll
    for (int l=0;l<4;l++){ int e=tid+l*256; int r=e>>5,c=e&31; double s=G[(size_t)r*N+c];
        #pragma unroll
        for (int kk=0;kk<32;kk++) s -= A[r][kk]*B[c][kk];
        acc[l]=s; }
    __syncthreads();
    #pragma unroll
    for (int l=0;l<4;l++){ int e=tid+l*256; D[e>>5][e&31]=acc[l]; }
    __syncthreads();
}
// D -= A*B^T (in place; each thread owns its 4 elements)
__device__ __forceinline__ void mm_nt_subL(double D[32][33], const double A[32][33],
                                           const double B[32][33], int tid){
    __syncthreads();
    double acc[4];
    #pragma unroll
    for (int l=0;l<4;l++){ int e=tid+l*256; int r=e>>5,c=e&31; double s=D[r][c];
        #pragma unroll
        for (int kk=0;kk<32;kk++) s -= A[r][kk]*B[c][kk];
        acc[l]=s; }
    __syncthreads();
    #pragma unroll
    for (int l=0;l<4;l++){ int e=tid+l*256; D[e>>5][e&31]=acc[l]; }
    __syncthreads();
}
// D -= A*B (in place)
__device__ __forceinline__ void mm_nn_subL(double D[32][33], const double A[32][33],
                                           const double B[32][33], int tid){
    __syncthreads();
    double acc[4];
    #pragma unroll
    for (int l=0;l<4;l++){ int e=tid+l*256; int r=e>>5,c=e&31; double s=D[r][c];
        #pragma unroll
        for (int kk=0;kk<32;kk++) s -= A[r][kk]*B[kk][c];
        acc[l]=s; }
    __syncthreads();
    #pragma unroll
    for (int l=0;l<4;l++){ int e=tid+l*256; D[e>>5][e&31]=acc[l]; }
    __syncthreads();
}
// D = -P - A^T*Z  (case (k,k): A=W^T so A^T*Z = W*Z)
__device__ __forceinline__ void mm_negtn(double D[32][33], const double P[32][33],
                                         const double A[32][33], const double Z[32][33], int tid){
    __syncthreads();
    double acc[4];
    #pragma unroll
    for (int l=0;l<4;l++){ int e=tid+l*256; int r=e>>5,c=e&31; double s=-P[r][c];
        #pragma unroll
        for (int kk=0;kk<32;kk++) s -= A[kk][r]*Z[kk][c];
        acc[l]=s; }
    __syncthreads();
    #pragma unroll
    for (int l=0;l<4;l++){ int e=tid+l*256; D[e>>5][e&31]=acc[l]; }
    __syncthreads();
}

// ------- fused gather + distances + kernel matrices + bnum partials ---------
__global__ void k_dist(const float* __restrict__ z1, const float* __restrict__ z2,
                       const int* __restrict__ p1, const int* __restrict__ p2,
                       double* __restrict__ S0, float* __restrict__ M4,
                       float* __restrict__ U4, double* __restrict__ bpart){
    __shared__ float Xs[16][17], Ys[16][17];
    int w = blockIdx.z;
    int tx = threadIdx.x, ty = threadIdx.y;
    int row = blockIdx.y*16 + ty, col = blockIdx.x*16 + tx;
    const float *Xb[2], *Yb[2]; const int *Xp[2], *Yp[2]; int npair = 1;
    Xb[1]=0; Yb[1]=0; Xp[0]=0; Yp[0]=0; Xp[1]=0; Yp[1]=0;
    switch(w){
        case 0: Xb[0]=z1; Yb[0]=z1; Xb[1]=z2; Yb[1]=z2; npair=2; break;
        case 1: Xb[0]=z1; Yb[0]=z1; Yp[0]=p1; Xb[1]=z2; Yb[1]=z2; Yp[1]=p2; npair=2; break;
        case 2: Xb[0]=z2; Yb[0]=z2; Xp[0]=p2; Yp[0]=p2; break;
        case 3: Xb[0]=z2; Yb[0]=z2; Xp[0]=p2; break;
        default:Xb[0]=z1; Yb[0]=z2; break;
    }
    double acc = 0.0;
    for (int p = 0; p < npair; p++){
        const float* X = Xb[p]; const float* Y = Yb[p];
        int xr = blockIdx.y*16 + ty; if (Xp[p]) xr = Xp[p][xr];
        int yr = blockIdx.x*16 + ty; if (Yp[p]) yr = Yp[p][yr];
        for (int c = 0; c < Dd; c += 16){
            __syncthreads();
            Xs[ty][tx] = X[xr*Dd + c + tx];
            Ys[ty][tx] = Y[yr*Dd + c + tx];
            __syncthreads();
            #pragma unroll
            for (int t = 0; t < 16; t++){
                float d = Xs[ty][t] - Ys[tx][t];
                acc += (double)d * (double)d;
            }
        }
    }
    int o = row*N + col;
    if (w == 0){
        #pragma unroll
        for (int s = 0; s < 4; s++){
            double v = exp(-inv2s2_of(s)*acc);
            if (row == col) v += 1.0e-3;
            S0[(size_t)(4+s)*N*N + o] = v;
        }
    } else if (w == 1){
        #pragma unroll
        for (int s = 0; s < 4; s++){
            double v = exp(-inv2s2_of(s)*acc);
            v += __shfl_down(v, 8, 16);
            v += __shfl_down(v, 4, 16);
            v += __shfl_down(v, 2, 16);
            v += __shfl_down(v, 1, 16);
            if (tx == 0) bpart[((size_t)s*N + row)*16 + blockIdx.x] = v;
        }
    } else if (w == 2){
        #pragma unroll
        for (int s = 0; s < 4; s++){
            double v = exp(-inv2s2_of(s)*acc);
            if (row == col) v += 1.0e-3;
            S0[(size_t)s*N*N + o] = v;
        }
    } else if (w == 3){
        #pragma unroll
        for (int s = 0; s < 4; s++) M4[s*N*N + o] = (float)exp(-inv2s2_of(s)*acc);
    } else {
        #pragma unroll
        for (int s = 0; s < 4; s++) U4[s*N*N + o] = (float)exp(-inv2s2_of(s)*acc);
    }
}

// ------ B = M*U^T (f32 in, f64 out); z=4 slice: pivot0 sweep + dsum zero ------
__global__ void k_gemm_nt(const float* __restrict__ M4, const float* __restrict__ U4,
                          double* __restrict__ Bmat, const double* __restrict__ S0,
                          double* __restrict__ Pg0, double* __restrict__ dsum){
    __shared__ float Ms[32][33], Us[32][33];
    __shared__ double P[32][33];
    int tx = threadIdx.x, ty = threadIdx.y;
    int tid = ty*16 + tx;
    if (blockIdx.z == 4){
        if (blockIdx.y != 0) return;
        int mat = blockIdx.x;
        if (mat == 0) dsum[tid] = 0.0;
        const double* S = S0 + (size_t)mat*65536;
        #pragma unroll
        for (int l = 0; l < 4; l++){
            int e = tid + l*256; P[e>>5][e&31] = S[(size_t)(e>>5)*N + (e&31)];
        }
        __syncthreads();
        sweep32(P, tid);
        __syncthreads();
        double* Pp = Pg0 + (size_t)mat*1024;
        #pragma unroll
        for (int l = 0; l < 4; l++){
            int e = tid + l*256; Pp[e] = P[e>>5][e&31];
        }
        return;
    }
    int s = blockIdx.z;
    const float* Mp = M4 + s*N*N;
    const float* Up = U4 + s*N*N;
    double* Bp = Bmat + s*N*N;
    int bj = blockIdx.y*32, bi = blockIdx.x*32;
    double a00=0, a01=0, a10=0, a11=0;
    for (int kc = 0; kc < N; kc += 32){
        __syncthreads();
        #pragma unroll
        for (int l = 0; l < 4; l++){
            int e = tid + l*256; int r = e >> 5, c = e & 31;
            Ms[r][c] = Mp[(bj+r)*N + kc + c];
            Us[r][c] = Up[(bi+r)*N + kc + c];
        }
        __syncthreads();
        #pragma unroll
        for (int k = 0; k < 32; k++){
            float x0 = Ms[2*ty][k], x1 = Ms[2*ty+1][k];
            float y0 = Us[2*tx][k], y1 = Us[2*tx+1][k];
            a00 += (double)x0*y0; a01 += (double)x0*y1;
            a10 += (double)x1*y0; a11 += (double)x1*y1;
        }
    }
    Bp[(bj+2*ty  )*N + bi+2*tx  ] = a00;
    Bp[(bj+2*ty  )*N + bi+2*tx+1] = a01;
    Bp[(bj+2*ty+1)*N + bi+2*tx  ] = a10;
    Bp[(bj+2*ty+1)*N + bi+2*tx+1] = a11;
}

// ====== fused double GJ step: pivots k and q=k+1 in ONE launch ==============
// No cross-block sync: every block redundantly computes P_q = inv(A_qq) from
// the source matrix + P_k. Symmetric invariant (R4-verified) exploited: only
// lower-tri tiles computed, mirrors via LDS transpose. grid (36, 8).
// Step-k formulas (verified in R4 k_step): for pivot p, E_t = S(t,p):
//   D(a,b) = S(a,b) - E_a*P*E_b^T ;  D(t,p) = E_t*P ;  D(p,t) = (E_t*P)^T ;
//   D(p,p) = -P.  Applied twice with P_k then P_q.
__global__ void __launch_bounds__(256) k_step2(
    const double* __restrict__ Ssrc, double* __restrict__ Sdst,
    const double* __restrict__ PgS, double* __restrict__ PgD, int k)
{
    __shared__ double T0[32][33], T1[32][33], T2[32][33], T3[32][33],
                      T4[32][33], T5[32][33], T6[32][33];
    int tid = threadIdx.x;
    int mat = blockIdx.y;
    const double* S = Ssrc + (size_t)mat*65536;
    double* D = Sdst + (size_t)mat*65536;
    int q = k + 1, nk = k + 2;
    // decode lower-tri tile (a,b), a>=b, from blockIdx.x in 0..35
    int a = 0, bb = blockIdx.x;
    while (bb >= a+1){ bb -= a+1; a++; }
    int b = bb;
    auto TS = [&](int r, int c){ return S + (size_t)(r*32)*N + c*32; };
    auto TD = [&](int r, int c){ return D + (size_t)(r*32)*N + c*32; };

    // prologue (all blocks): T0=Pk, T1=Ekq=S(q,k), T2=W^T=Ekq*Pk,
    // T3=A_qq=S(q,q)-W^T*Ekq^T -> sweep -> P_q
    ld_pg(T0, PgS + (size_t)mat*1024, tid);
    ld_tile(T1, TS(q,k), tid);
    mm_nn(T2, T1, T0, tid);
    mm_nt_subG(T3, TS(q,q), T2, T1, tid);
    __syncthreads(); sweep32(T3, tid); __syncthreads();

    if (a == q && b == q){
        // (q,q): D2 = -P_q
        __syncthreads();
        double* G = TD(q,q);
        #pragma unroll
        for (int l=0;l<4;l++){ int e=tid+l*256; int r=e>>5,c=e&31; G[(size_t)r*N+c] = -T3[r][c]; }
    } else if (a == k && b == k){
        // (k,k): D2 = -Pk - W*P_q*W^T ; Z = P_q*W^T = T3*T2
        mm_nn(T4, T3, T2, tid);
        mm_negtn(T5, T0, T2, T4, tid);
        st_tile(TD(k,k), T5, tid);
    } else if (a == q && b == k){
        // (q,k): D2(q,k) = P_q*W^T ; mirror (k,q) = (P_q*W^T)^T = W*P_q
        mm_nn(T4, T3, T2, tid);
        st_tile (TD(q,k), T4, tid);
        st_tileT(TD(k,q), T4, tid);
    } else if (b == k || a == k){
        // one index k, other x notin {k,q}: M = Ex*Pk - G1x*P_q*W^T
        int x = (b == k) ? a : b;
        ld_tile(T4, TS(x,k), tid);
        mm_nn(T5, T4, T0, tid);                  // Ex*Pk
        mm_nt_subG(T6, TS(x,q), T5, T1, tid);    // G1x = S(x,q) - Ex*Pk*Ekq^T
        mm_nn(T4, T6, T3, tid);                  // U = G1x*P_q
        mm_nn_subL(T5, T4, T2, tid);             // M = Ex*Pk - U*W^T  (W^T=T2, NN)
        st_tile (TD(x,k), T5, tid);
        st_tileT(TD(k,x), T5, tid);
    } else if (a == q || b == q){
        // one index q, other x notin {k,q}: M = G1x*P_q
        int x = (a == q) ? b : a;
        ld_tile(T4, TS(x,k), tid);
        mm_nn(T5, T4, T0, tid);
        mm_nt_subG(T6, TS(x,q), T5, T1, tid);
        mm_nn(T4, T6, T3, tid);                  // U = G1x*P_q
        st_tile (TD(x,q), T4, tid);
        st_tileT(TD(q,x), T4, tid);
    } else {
        // generic a,b notin {k,q} (incl. a==b):
        // D2 = S(a,b) - Ea*Pk*Eb^T - G1a*P_q*G1b^T
        ld_tile(T4, TS(a,k), tid);
        mm_nn(T5, T4, T0, tid);                  // tmpA = Ea*Pk
        mm_nt_subG(T2, TS(a,q), T5, T1, tid);    // G1a (overwrites W^T - unused here)
        ld_tile(T4, TS(b,k), tid);               // Eb
        mm_nn(T6, T4, T0, tid);                  // tmpB = Eb*Pk
        mm_nt_subG(T0, TS(b,q), T6, T1, tid);    // G1b (overwrites Pk - dead)
        mm_nn(T6, T2, T3, tid);                  // U = G1a*P_q (overwrites tmpB)
        mm_nt_subG(T1, TS(a,b), T5, T4, tid);    // S(a,b) - tmpA*Eb^T (overwrites Ekq)
        mm_nt_subL(T1, T6, T0, tid);             // -= U*G1b^T
        st_tile(TD(a,b), T1, tid);
        if (a != b) st_tileT(TD(b,a), T1, tid);
        // fold pivot sweep for next launch: inv of D2(nk,nk)
        if (a == nk && b == nk && k < 6){
            __syncthreads(); sweep32(T1, tid); __syncthreads();
            double* Pd = PgD + (size_t)mat*1024;
            #pragma unroll
            for (int l=0;l<4;l++){ int e=tid+l*256; Pd[e] = T1[e>>5][e&31]; }
        }
    }
}

// ------ X[s] = G[s]*B[s] in f64 (G = -Sfin) ------
__global__ void k_x(const double* __restrict__ Sfin, const double* __restrict__ Bmat,
                    float* __restrict__ Xm){
    int s = blockIdx.z;
    const double* Sp = Sfin + (size_t)s*N*N;
    const double* Bp = Bmat + (size_t)s*N*N;
    float* Xp = Xm + (size_t)s*N*N;
    __shared__ double Gs[32][33], Bs[32][33];
    int tx = threadIdx.x, ty = threadIdx.y;
    int tid = ty*16 + tx;
    int bj = blockIdx.y*32, bi = blockIdx.x*32;
    double a00=0, a01=0, a10=0, a11=0;
    for (int kc = 0; kc < N; kc += 32){
        __syncthreads();
        #pragma unroll
        for (int l = 0; l < 4; l++){
            int e = tid + l*256; int r = e >> 5, c = e & 31;
            Gs[r][c] = -Sp[(size_t)(bj+r)*N + kc + c];
            Bs[r][c] = Bp[(size_t)(kc+r)*N + bi + c];
        }
        __syncthreads();
        #pragma unroll
        for (int k = 0; k < 32; k++){
            double x0 = Gs[2*ty][k], x1 = Gs[2*ty+1][k];
            double y0 = Bs[k][2*tx], y1 = Bs[k][2*tx+1];
            a00 += x0*y0; a01 += x0*y1;
            a10 += x1*y0; a11 += x1*y1;
        }
    }
    Xp[(bj+2*ty  )*N + bi+2*tx  ] = (float)a00;
    Xp[(bj+2*ty  )*N + bi+2*tx+1] = (float)a01;
    Xp[(bj+2*ty+1)*N + bi+2*tx  ] = (float)a10;
    Xp[(bj+2*ty+1)*N + bi+2*tx+1] = (float)a11;
}

// ---- b<64: relu(avg over sigma of Xm) column sums -> dsum (f64 atomics).
// ---- b in 64..67: numerator solve rnum[s] = Gnum*b (coalesced via symmetry).
__global__ void k_red(const float* __restrict__ Xm, const double* __restrict__ Sfin,
                      const double* __restrict__ bpart, double* __restrict__ dsum,
                      float* __restrict__ rnum){
    __shared__ double cp[32][33];
    __shared__ double bsh[256];
    int b = blockIdx.x, tid = threadIdx.x;
    if (b < 64){
        int bj = (b >> 3)*32, bi = (b & 7)*32;
        #pragma unroll
        for (int l = 0; l < 4; l++){
            int e = tid + l*256; int r = e >> 5, c = e & 31;
            int o = (bj + r)*N + bi + c;
            float x = Xm[0*N*N + o] + Xm[1*N*N + o] + Xm[2*N*N + o] + Xm[3*N*N + o];
            cp[r][c] = (double)fmaxf(0.25f*x, 0.f);
        }
        __syncthreads();
        if (tid < 32){
            double ssum = 0;
            #pragma unroll
            for (int r = 0; r < 32; r++) ssum += cp[r][tid];
            atomicAdd(&dsum[bi + tid], ssum);
        }
    } else {
        int s = b - 64, j = tid;
        const double* Sn = Sfin + (size_t)(4+s)*N*N;
        const double* bp = bpart + (size_t)s*N*16;
        double acc = 0;
        #pragma unroll
        for (int t = 0; t < 16; t++) acc += bp[j*16 + t];
        bsh[j] = acc;
        __syncthreads();
        double y = 0;
        for (int k = 0; k < N; k++) y -= Sn[(size_t)k*N + j] * bsh[k];
        rnum[s*N + j] = (float)y;
    }
}

// ---------------- final loss ----------------
__global__ void k_loss2(const double* __restrict__ dsum, const float* __restrict__ rnum,
                        float* __restrict__ out){
    __shared__ double red[256];
    int i = threadIdx.x;
    double denum = dsum[i] + (double)N * 1.0e-3;
    float ravg = 0.25f*(rnum[0*N+i] + rnum[1*N+i] + rnum[2*N+i] + rnum[3*N+i]);
    double rn = (double)fmaxf(ravg, 0.f) + 1.0e-3;
    red[i] = log(rn) + log(denum);
    __syncthreads();
    for (int st = 128; st > 0; st >>= 1){
        if (i < st) red[i] += red[i + st];
        __syncthreads();
    }
    if (i == 0) out[0] = (float)red[0];
}

extern "C" void kernel_launch(void* const* d_in, const int* in_sizes, int n_in,
                              void* d_out, int out_size, void* d_ws, size_t ws_size,
                              hipStream_t stream) {
    (void)in_sizes; (void)n_in; (void)out_size; (void)ws_size;
    const float* z1 = (const float*)d_in[0];
    const float* z2 = (const float*)d_in[1];
    const int*   p1 = (const int*)d_in[2];
    const int*   p2 = (const int*)d_in[3];
    float* out = (float*)d_out;

    char* w = (char*)d_ws;
    size_t o = 0;
    auto carve = [&](size_t bytes) -> char* {
        char* p = w + o;
        o += (bytes + 255) & ~(size_t)255;
        return p;
    };
    double* bpart = (double*)carve((size_t)4*N*16*sizeof(double));
    double* dsum  = (double*)carve((size_t)N*sizeof(double));
    float*  M4    = (float*) carve((size_t)4*N*N*sizeof(float));
    float*  U4    = (float*) carve((size_t)4*N*N*sizeof(float));
    double* Bmat  = (double*)carve((size_t)4*N*N*sizeof(double));
    float*  Xm    = (float*) carve((size_t)4*N*N*sizeof(float));
    float*  rnum  = (float*) carve((size_t)4*N*sizeof(float));
    double* S0    = (double*)carve((size_t)8*N*N*sizeof(double));  // ping
    double* S1    = (double*)carve((size_t)8*N*N*sizeof(double));  // pong
    double* Pg0   = (double*)carve((size_t)8*32*32*sizeof(double));
    double* Pg1   = (double*)carve((size_t)8*32*32*sizeof(double));

    k_dist<<<dim3(16,16,5), dim3(16,16), 0, stream>>>(z1, z2, p1, p2,
                                                      S0, M4, U4, bpart);
    k_gemm_nt<<<dim3(8,8,5), dim3(16,16), 0, stream>>>(M4, U4, Bmat, S0, Pg0, dsum);
    // 4 fused double-steps: k = 0,2,4,6 ; ping-pong S0<->S1, Pg0<->Pg1
    for (int j = 0; j < 4; j++){
        int k = 2*j;
        double* src = (j & 1) ? S1 : S0;
        double* dst = (j & 1) ? S0 : S1;
        double* ps  = (j & 1) ? Pg1 : Pg0;
        double* pd  = (j & 1) ? Pg0 : Pg1;
        k_step2<<<dim3(36,8), dim3(256), 0, stream>>>(src, dst, ps, pd, k);
    }
    // after j=3 (odd): final swept matrices in S0
    k_x<<<dim3(8,8,4), dim3(16,16), 0, stream>>>(S0, Bmat, Xm);
    k_red<<<dim3(68), dim3(256), 0, stream>>>(Xm, S0, bpart, dsum, rnum);
    k_loss2<<<dim3(1), dim3(256), 0, stream>>>(dsum, rnum, out);
}

// Round 10
// 452.062 us; speedup vs baseline: 1.3917x; 1.3917x over previous
//
#include <hip/hip_runtime.h>
#include <math.h>

#define N 256
#define Dd 128

__device__ __forceinline__ double inv2s2_of(int s){
    return (s==0)?0.5:(s==1)?5.0e-3:(s==2)?5.0e-5:5.0e-7;
}

// verified elementwise f64 GJ sweep of a 32x32 LDS tile.
// After the loop the swept tile = -D^{-1}; negate so P = D^{-1}.
__device__ __forceinline__ void sweep32(double P[32][33], int tid){
    if (tid < 64){
        int r = tid & 31, cg_ = tid >> 5;
        for (int j = 0; j < 32; j++){
            double d    = P[j][j];
            double invd = 1.0 / d;
            double cr   = P[r][j];
            double s    = cr * invd;
            bool rj = (r == j);
            double nv[16];
            #pragma unroll
            for (int c = 0; c < 16; c++){
                int col = cg_*16 + c;
                double pj = P[j][col];
                double v  = P[r][col];
                nv[c] = rj ? ((col == j) ? -invd : v * invd)
                           : ((col == j) ? s : v - s*pj);
            }
            #pragma unroll
            for (int c = 0; c < 16; c++) P[r][cg_*16+c] = nv[c];
        }
        #pragma unroll
        for (int c = 0; c < 16; c++) P[r][cg_*16+c] = -P[r][cg_*16+c];
    }
}

// ------- fused gather + distances + kernel matrices + bnum partials ---------
__global__ void k_dist(const float* __restrict__ z1, const float* __restrict__ z2,
                       const int* __restrict__ p1, const int* __restrict__ p2,
                       double* __restrict__ S0, float* __restrict__ M4,
                       float* __restrict__ U4, double* __restrict__ bpart){
    __shared__ float Xs[16][17], Ys[16][17];
    int w = blockIdx.z;
    int tx = threadIdx.x, ty = threadIdx.y;
    int row = blockIdx.y*16 + ty, col = blockIdx.x*16 + tx;
    const float *Xb[2], *Yb[2]; const int *Xp[2], *Yp[2]; int npair = 1;
    Xb[1]=0; Yb[1]=0; Xp[0]=0; Yp[0]=0; Xp[1]=0; Yp[1]=0;
    switch(w){
        case 0: Xb[0]=z1; Yb[0]=z1; Xb[1]=z2; Yb[1]=z2; npair=2; break;
        case 1: Xb[0]=z1; Yb[0]=z1; Yp[0]=p1; Xb[1]=z2; Yb[1]=z2; Yp[1]=p2; npair=2; break;
        case 2: Xb[0]=z2; Yb[0]=z2; Xp[0]=p2; Yp[0]=p2; break;
        case 3: Xb[0]=z2; Yb[0]=z2; Xp[0]=p2; break;
        default:Xb[0]=z1; Yb[0]=z2; break;
    }
    double acc = 0.0;
    for (int p = 0; p < npair; p++){
        const float* X = Xb[p]; const float* Y = Yb[p];
        int xr = blockIdx.y*16 + ty; if (Xp[p]) xr = Xp[p][xr];
        int yr = blockIdx.x*16 + ty; if (Yp[p]) yr = Yp[p][yr];
        for (int c = 0; c < Dd; c += 16){
            __syncthreads();
            Xs[ty][tx] = X[xr*Dd + c + tx];
            Ys[ty][tx] = Y[yr*Dd + c + tx];
            __syncthreads();
            #pragma unroll
            for (int t = 0; t < 16; t++){
                float d = Xs[ty][t] - Ys[tx][t];
                acc += (double)d * (double)d;
            }
        }
    }
    int o = row*N + col;
    if (w == 0){
        #pragma unroll
        for (int s = 0; s < 4; s++){
            double v = exp(-inv2s2_of(s)*acc);
            if (row == col) v += 1.0e-3;
            S0[(size_t)(4+s)*N*N + o] = v;
        }
    } else if (w == 1){
        #pragma unroll
        for (int s = 0; s < 4; s++){
            double v = exp(-inv2s2_of(s)*acc);
            v += __shfl_down(v, 8, 16);
            v += __shfl_down(v, 4, 16);
            v += __shfl_down(v, 2, 16);
            v += __shfl_down(v, 1, 16);
            if (tx == 0) bpart[((size_t)s*N + row)*16 + blockIdx.x] = v;
        }
    } else if (w == 2){
        #pragma unroll
        for (int s = 0; s < 4; s++){
            double v = exp(-inv2s2_of(s)*acc);
            if (row == col) v += 1.0e-3;
            S0[(size_t)s*N*N + o] = v;
        }
    } else if (w == 3){
        #pragma unroll
        for (int s = 0; s < 4; s++) M4[s*N*N + o] = (float)exp(-inv2s2_of(s)*acc);
    } else {
        #pragma unroll
        for (int s = 0; s < 4; s++) U4[s*N*N + o] = (float)exp(-inv2s2_of(s)*acc);
    }
}

// ------ B = M*U^T (f32 in, f64 out); z=4 slice: pivot0 sweep + dsum zero ------
__global__ void k_gemm_nt(const float* __restrict__ M4, const float* __restrict__ U4,
                          double* __restrict__ Bmat, const double* __restrict__ S0,
                          double* __restrict__ Pg0, double* __restrict__ dsum){
    __shared__ float Ms[32][33], Us[32][33];
    __shared__ double P[32][33];
    int tx = threadIdx.x, ty = threadIdx.y;
    int tid = ty*16 + tx;
    if (blockIdx.z == 4){
        if (blockIdx.y != 0) return;
        int mat = blockIdx.x;
        if (mat == 0) dsum[tid] = 0.0;
        const double* S = S0 + (size_t)mat*65536;
        #pragma unroll
        for (int l = 0; l < 4; l++){
            int e = tid + l*256; P[e>>5][e&31] = S[(size_t)(e>>5)*N + (e&31)];
        }
        __syncthreads();
        sweep32(P, tid);
        __syncthreads();
        double* Pp = Pg0 + (size_t)mat*1024;
        #pragma unroll
        for (int l = 0; l < 4; l++){
            int e = tid + l*256; Pp[e] = P[e>>5][e&31];
        }
        return;
    }
    int s = blockIdx.z;
    const float* Mp = M4 + s*N*N;
    const float* Up = U4 + s*N*N;
    double* Bp = Bmat + s*N*N;
    int bj = blockIdx.y*32, bi = blockIdx.x*32;
    double a00=0, a01=0, a10=0, a11=0;
    for (int kc = 0; kc < N; kc += 32){
        __syncthreads();
        #pragma unroll
        for (int l = 0; l < 4; l++){
            int e = tid + l*256; int r = e >> 5, c = e & 31;
            Ms[r][c] = Mp[(bj+r)*N + kc + c];
            Us[r][c] = Up[(bi+r)*N + kc + c];
        }
        __syncthreads();
        #pragma unroll
        for (int k = 0; k < 32; k++){
            float x0 = Ms[2*ty][k], x1 = Ms[2*ty+1][k];
            float y0 = Us[2*tx][k], y1 = Us[2*tx+1][k];
            a00 += (double)x0*y0; a01 += (double)x0*y1;
            a10 += (double)x1*y0; a11 += (double)x1*y1;
        }
    }
    Bp[(bj+2*ty  )*N + bi+2*tx  ] = a00;
    Bp[(bj+2*ty  )*N + bi+2*tx+1] = a01;
    Bp[(bj+2*ty+1)*N + bi+2*tx  ] = a10;
    Bp[(bj+2*ty+1)*N + bi+2*tx+1] = a11;
}

// ====== blocked f64 GJ step, symmetry-aware, 1024 threads/block =====
// grid (35, 8). Each thread owns ONE 32x32-tile element (r=tid>>5, c=tid&31):
// per-mm FMA chain is 32 (was 128 at 256 thr), and 16 waves/block = 4
// waves/SIMD hide LDS latency (R4/R9 showed duration == one block's serial
// LDS-latency chain; VALUBusy 1.7% at 1 wave/SIMD).
// bx<28: lower-tri trailing tile (I>=J), mirror via LDS transpose.
// bx>=28: col/row panel T (+pivot for T==0). Numerics identical to R4.
__global__ void __launch_bounds__(1024) k_step(
    const double* __restrict__ Ssrc, double* __restrict__ Sdst,
    const double* __restrict__ PgS, double* __restrict__ PgD, int k)
{
    __shared__ double Pl[32][33], EJ[32][33], Cl[32][33], El[32][33];
    int bx = blockIdx.x, mat = blockIdx.y;
    const double* S = Ssrc + (size_t)mat*65536;
    double* D = Sdst + (size_t)mat*65536;
    const double* Pp = PgS + (size_t)mat*1024;
    int tid = threadIdx.x;
    int r = tid >> 5, c = tid & 31;
    int Kb = k*32;
    if (bx < 28){
        int I = 0, b = bx;
        while (b >= I+1){ b -= I+1; I++; }
        int J = b;
        int GI = ((I < k) ? I : I + 1) * 32;
        int GJ = ((J < k) ? J : J + 1) * 32;
        // register-stage the 4 global loads (all in flight), then LDS writes
        double rP  = Pp[tid];
        double rE  = S[(size_t)(GI + r)*N + Kb + c];
        double rEJ = S[(size_t)(GJ + r)*N + Kb + c];
        double a   = S[(size_t)(GI + r)*N + GJ + c];
        Pl[r][c] = rP;
        El[r][c] = rE;
        EJ[r][c] = rEJ;
        __syncthreads();
        double acc = 0.0;
        #pragma unroll
        for (int kk = 0; kk < 32; kk++) acc += EJ[r][kk] * Pl[kk][c];
        Cl[r][c] = acc;
        __syncthreads();
        #pragma unroll
        for (int kk = 0; kk < 32; kk++) a -= El[r][kk] * Cl[c][kk];
        D[(size_t)(GI + r)*N + GJ + c] = a;
        if (I != J){
            // mirror: D(GJ,GI) = D(GI,GJ)^T via LDS (EJ dead, reuse)
            __syncthreads();
            EJ[r][c] = a;
            __syncthreads();
            D[(size_t)(GJ + r)*N + GI + c] = EJ[c][r];
        } else if (I == k && k < 7){
            // fold next pivot sweep: this block produced dst tile (k+1,k+1)
            __syncthreads();
            El[r][c] = a;
            __syncthreads();
            sweep32(El, tid);
            __syncthreads();
            PgD[(size_t)mat*1024 + tid] = El[r][c];
        }
    } else {
        int T = bx - 28;
        int GT = ((T < k) ? T : T + 1) * 32;
        double rP = Pp[tid];
        double rE = S[(size_t)(GT + r)*N + Kb + c];
        Pl[r][c] = rP;
        El[r][c] = rE;
        __syncthreads();
        double acc = 0.0;
        #pragma unroll
        for (int kk = 0; kk < 32; kk++) acc += El[r][kk] * Pl[kk][c];
        Cl[r][c] = acc;
        __syncthreads();
        D[(size_t)(GT + r)*N + Kb + c] = Cl[r][c];       // col block
        D[(size_t)(Kb + r)*N + GT + c] = Cl[c][r];       // row block = C^T
        if (T == 0)
            D[(size_t)(Kb + r)*N + Kb + c] = -Pl[r][c];  // pivot block
    }
}

// ------ X[s] = G[s]*B[s] in f64 (G = -Sfin) ------
__global__ void k_x(const double* __restrict__ Sfin, const double* __restrict__ Bmat,
                    float* __restrict__ Xm){
    int s = blockIdx.z;
    const double* Sp = Sfin + (size_t)s*N*N;
    const double* Bp = Bmat + (size_t)s*N*N;
    float* Xp = Xm + (size_t)s*N*N;
    __shared__ double Gs[32][33], Bs[32][33];
    int tx = threadIdx.x, ty = threadIdx.y;
    int tid = ty*16 + tx;
    int bj = blockIdx.y*32, bi = blockIdx.x*32;
    double a00=0, a01=0, a10=0, a11=0;
    for (int kc = 0; kc < N; kc += 32){
        __syncthreads();
        #pragma unroll
        for (int l = 0; l < 4; l++){
            int e = tid + l*256; int r = e >> 5, c = e & 31;
            Gs[r][c] = -Sp[(size_t)(bj+r)*N + kc + c];
            Bs[r][c] = Bp[(size_t)(kc+r)*N + bi + c];
        }
        __syncthreads();
        #pragma unroll
        for (int k = 0; k < 32; k++){
            double x0 = Gs[2*ty][k], x1 = Gs[2*ty+1][k];
            double y0 = Bs[k][2*tx], y1 = Bs[k][2*tx+1];
            a00 += x0*y0; a01 += x0*y1;
            a10 += x1*y0; a11 += x1*y1;
        }
    }
    Xp[(bj+2*ty  )*N + bi+2*tx  ] = (float)a00;
    Xp[(bj+2*ty  )*N + bi+2*tx+1] = (float)a01;
    Xp[(bj+2*ty+1)*N + bi+2*tx  ] = (float)a10;
    Xp[(bj+2*ty+1)*N + bi+2*tx+1] = (float)a11;
}

// ---- b<64: relu(avg over sigma of Xm) column sums -> dsum (f64 atomics).
// ---- b in 64..67: numerator solve rnum[s] = Gnum*b (coalesced via symmetry).
__global__ void k_red(const float* __restrict__ Xm, const double* __restrict__ Sfin,
                      const double* __restrict__ bpart, double* __restrict__ dsum,
                      float* __restrict__ rnum){
    __shared__ double cp[32][33];
    __shared__ double bsh[256];
    int b = blockIdx.x, tid = threadIdx.x;
    if (b < 64){
        int bj = (b >> 3)*32, bi = (b & 7)*32;
        #pragma unroll
        for (int l = 0; l < 4; l++){
            int e = tid + l*256; int r = e >> 5, c = e & 31;
            int o = (bj + r)*N + bi + c;
            float x = Xm[0*N*N + o] + Xm[1*N*N + o] + Xm[2*N*N + o] + Xm[3*N*N + o];
            cp[r][c] = (double)fmaxf(0.25f*x, 0.f);
        }
        __syncthreads();
        if (tid < 32){
            double ssum = 0;
            #pragma unroll
            for (int r = 0; r < 32; r++) ssum += cp[r][tid];
            atomicAdd(&dsum[bi + tid], ssum);
        }
    } else {
        int s = b - 64, j = tid;
        const double* Sn = Sfin + (size_t)(4+s)*N*N;
        const double* bp = bpart + (size_t)s*N*16;
        double acc = 0;
        #pragma unroll
        for (int t = 0; t < 16; t++) acc += bp[j*16 + t];
        bsh[j] = acc;
        __syncthreads();
        double y = 0;
        for (int k = 0; k < N; k++) y -= Sn[(size_t)k*N + j] * bsh[k];
        rnum[s*N + j] = (float)y;
    }
}

// ---------------- final loss ----------------
__global__ void k_loss2(const double* __restrict__ dsum, const float* __restrict__ rnum,
                        float* __restrict__ out){
    __shared__ double red[256];
    int i = threadIdx.x;
    double denum = dsum[i] + (double)N * 1.0e-3;
    float ravg = 0.25f*(rnum[0*N+i] + rnum[1*N+i] + rnum[2*N+i] + rnum[3*N+i]);
    double rn = (double)fmaxf(ravg, 0.f) + 1.0e-3;
    red[i] = log(rn) + log(denum);
    __syncthreads();
    for (int st = 128; st > 0; st >>= 1){
        if (i < st) red[i] += red[i + st];
        __syncthreads();
    }
    if (i == 0) out[0] = (float)red[0];
}

extern "C" void kernel_launch(void* const* d_in, const int* in_sizes, int n_in,
                              void* d_out, int out_size, void* d_ws, size_t ws_size,
                              hipStream_t stream) {
    (void)in_sizes; (void)n_in; (void)out_size; (void)ws_size;
    const float* z1 = (const float*)d_in[0];
    const float* z2 = (const float*)d_in[1];
    const int*   p1 = (const int*)d_in[2];
    const int*   p2 = (const int*)d_in[3];
    float* out = (float*)d_out;

    char* w = (char*)d_ws;
    size_t o = 0;
    auto carve = [&](size_t bytes) -> char* {
        char* p = w + o;
        o += (bytes + 255) & ~(size_t)255;
        return p;
    };
    double* bpart = (double*)carve((size_t)4*N*16*sizeof(double));
    double* dsum  = (double*)carve((size_t)N*sizeof(double));
    float*  M4    = (float*) carve((size_t)4*N*N*sizeof(float));
    float*  U4    = (float*) carve((size_t)4*N*N*sizeof(float));
    double* Bmat  = (double*)carve((size_t)4*N*N*sizeof(double));
    float*  Xm    = (float*) carve((size_t)4*N*N*sizeof(float));
    float*  rnum  = (float*) carve((size_t)4*N*sizeof(float));
    double* S0    = (double*)carve((size_t)8*N*N*sizeof(double));  // ping
    double* S1    = (double*)carve((size_t)8*N*N*sizeof(double));  // pong
    double* Pg0   = (double*)carve((size_t)8*32*32*sizeof(double));
    double* Pg1   = (double*)carve((size_t)8*32*32*sizeof(double));

    k_dist<<<dim3(16,16,5), dim3(16,16), 0, stream>>>(z1, z2, p1, p2,
                                                      S0, M4, U4, bpart);
    k_gemm_nt<<<dim3(8,8,5), dim3(16,16), 0, stream>>>(M4, U4, Bmat, S0, Pg0, dsum);
    for (int k = 0; k < 8; k++){
        double* src = (k & 1) ? S1 : S0;
        double* dst = (k & 1) ? S0 : S1;
        double* ps  = (k & 1) ? Pg1 : Pg0;
        double* pd  = (k & 1) ? Pg0 : Pg1;
        k_step<<<dim3(35,8), dim3(1024), 0, stream>>>(src, dst, ps, pd, k);
    }
    // after k=7 (odd): final swept matrices in S0
    k_x<<<dim3(8,8,4), dim3(16,16), 0, stream>>>(S0, Bmat, Xm);
    k_red<<<dim3(68), dim3(256), 0, stream>>>(Xm, S0, bpart, dsum, rnum);
    k_loss2<<<dim3(1), dim3(256), 0, stream>>>(dsum, rnum, out);
}

// Round 11
// 440.264 us; speedup vs baseline: 1.4289x; 1.0268x over previous
//
#include <hip/hip_runtime.h>
#include <math.h>

#define N 256
#define Dd 128

__device__ __forceinline__ double inv2s2_of(int s){
    return (s==0)?0.5:(s==1)?5.0e-3:(s==2)?5.0e-5:5.0e-7;
}

// verified elementwise f64 GJ sweep of a 32x32 LDS tile.
// After the loop the swept tile = -D^{-1}; negate so P = D^{-1}.
__device__ __forceinline__ void sweep32(double P[32][33], int tid){
    if (tid < 64){
        int r = tid & 31, cg_ = tid >> 5;
        for (int j = 0; j < 32; j++){
            double d    = P[j][j];
            double invd = 1.0 / d;
            double cr   = P[r][j];
            double s    = cr * invd;
            bool rj = (r == j);
            double nv[16];
            #pragma unroll
            for (int c = 0; c < 16; c++){
                int col = cg_*16 + c;
                double pj = P[j][col];
                double v  = P[r][col];
                nv[c] = rj ? ((col == j) ? -invd : v * invd)
                           : ((col == j) ? s : v - s*pj);
            }
            #pragma unroll
            for (int c = 0; c < 16; c++) P[r][cg_*16+c] = nv[c];
        }
        #pragma unroll
        for (int c = 0; c < 16; c++) P[r][cg_*16+c] = -P[r][cg_*16+c];
    }
}

// ------- fused gather + distances + kernel matrices + bnum partials ---------
__global__ void k_dist(const float* __restrict__ z1, const float* __restrict__ z2,
                       const int* __restrict__ p1, const int* __restrict__ p2,
                       double* __restrict__ S0, float* __restrict__ M4,
                       float* __restrict__ U4, double* __restrict__ bpart){
    __shared__ float Xs[16][17], Ys[16][17];
    int w = blockIdx.z;
    int tx = threadIdx.x, ty = threadIdx.y;
    int row = blockIdx.y*16 + ty, col = blockIdx.x*16 + tx;
    const float *Xb[2], *Yb[2]; const int *Xp[2], *Yp[2]; int npair = 1;
    Xb[1]=0; Yb[1]=0; Xp[0]=0; Yp[0]=0; Xp[1]=0; Yp[1]=0;
    switch(w){
        case 0: Xb[0]=z1; Yb[0]=z1; Xb[1]=z2; Yb[1]=z2; npair=2; break;
        case 1: Xb[0]=z1; Yb[0]=z1; Yp[0]=p1; Xb[1]=z2; Yb[1]=z2; Yp[1]=p2; npair=2; break;
        case 2: Xb[0]=z2; Yb[0]=z2; Xp[0]=p2; Yp[0]=p2; break;
        case 3: Xb[0]=z2; Yb[0]=z2; Xp[0]=p2; break;
        default:Xb[0]=z1; Yb[0]=z2; break;
    }
    double acc = 0.0;
    for (int p = 0; p < npair; p++){
        const float* X = Xb[p]; const float* Y = Yb[p];
        int xr = blockIdx.y*16 + ty; if (Xp[p]) xr = Xp[p][xr];
        int yr = blockIdx.x*16 + ty; if (Yp[p]) yr = Yp[p][yr];
        for (int c = 0; c < Dd; c += 16){
            __syncthreads();
            Xs[ty][tx] = X[xr*Dd + c + tx];
            Ys[ty][tx] = Y[yr*Dd + c + tx];
            __syncthreads();
            #pragma unroll
            for (int t = 0; t < 16; t++){
                float d = Xs[ty][t] - Ys[tx][t];
                acc += (double)d * (double)d;
            }
        }
    }
    int o = row*N + col;
    if (w == 0){
        #pragma unroll
        for (int s = 0; s < 4; s++){
            double v = exp(-inv2s2_of(s)*acc);
            if (row == col) v += 1.0e-3;
            S0[(size_t)(4+s)*N*N + o] = v;
        }
    } else if (w == 1){
        #pragma unroll
        for (int s = 0; s < 4; s++){
            double v = exp(-inv2s2_of(s)*acc);
            v += __shfl_down(v, 8, 16);
            v += __shfl_down(v, 4, 16);
            v += __shfl_down(v, 2, 16);
            v += __shfl_down(v, 1, 16);
            if (tx == 0) bpart[((size_t)s*N + row)*16 + blockIdx.x] = v;
        }
    } else if (w == 2){
        #pragma unroll
        for (int s = 0; s < 4; s++){
            double v = exp(-inv2s2_of(s)*acc);
            if (row == col) v += 1.0e-3;
            S0[(size_t)s*N*N + o] = v;
        }
    } else if (w == 3){
        #pragma unroll
        for (int s = 0; s < 4; s++) M4[s*N*N + o] = (float)exp(-inv2s2_of(s)*acc);
    } else {
        #pragma unroll
        for (int s = 0; s < 4; s++) U4[s*N*N + o] = (float)exp(-inv2s2_of(s)*acc);
    }
}

// ------ B = M*U^T (f32 in, f64 out); z=4 slice: pivot0 sweep + dsum zero ------
__global__ void k_gemm_nt(const float* __restrict__ M4, const float* __restrict__ U4,
                          double* __restrict__ Bmat, const double* __restrict__ S0,
                          double* __restrict__ Pg0, double* __restrict__ dsum){
    __shared__ float Ms[32][33], Us[32][33];
    __shared__ double P[32][33];
    int tx = threadIdx.x, ty = threadIdx.y;
    int tid = ty*16 + tx;
    if (blockIdx.z == 4){
        if (blockIdx.y != 0) return;
        int mat = blockIdx.x;
        if (mat == 0) dsum[tid] = 0.0;
        const double* S = S0 + (size_t)mat*65536;
        #pragma unroll
        for (int l = 0; l < 4; l++){
            int e = tid + l*256; P[e>>5][e&31] = S[(size_t)(e>>5)*N + (e&31)];
        }
        __syncthreads();
        sweep32(P, tid);
        __syncthreads();
        double* Pp = Pg0 + (size_t)mat*1024;
        #pragma unroll
        for (int l = 0; l < 4; l++){
            int e = tid + l*256; Pp[e] = P[e>>5][e&31];
        }
        return;
    }
    int s = blockIdx.z;
    const float* Mp = M4 + s*N*N;
    const float* Up = U4 + s*N*N;
    double* Bp = Bmat + s*N*N;
    int bj = blockIdx.y*32, bi = blockIdx.x*32;
    double a00=0, a01=0, a10=0, a11=0;
    for (int kc = 0; kc < N; kc += 32){
        __syncthreads();
        #pragma unroll
        for (int l = 0; l < 4; l++){
            int e = tid + l*256; int r = e >> 5, c = e & 31;
            Ms[r][c] = Mp[(bj+r)*N + kc + c];
            Us[r][c] = Up[(bi+r)*N + kc + c];
        }
        __syncthreads();
        #pragma unroll
        for (int k = 0; k < 32; k++){
            float x0 = Ms[2*ty][k], x1 = Ms[2*ty+1][k];
            float y0 = Us[2*tx][k], y1 = Us[2*tx+1][k];
            a00 += (double)x0*y0; a01 += (double)x0*y1;
            a10 += (double)x1*y0; a11 += (double)x1*y1;
        }
    }
    Bp[(bj+2*ty  )*N + bi+2*tx  ] = a00;
    Bp[(bj+2*ty  )*N + bi+2*tx+1] = a01;
    Bp[(bj+2*ty+1)*N + bi+2*tx  ] = a10;
    Bp[(bj+2*ty+1)*N + bi+2*tx+1] = a11;
}

// ====== blocked f64 GJ step, symmetry-aware, LDS-traffic-minimized =====
// grid (35, 8), 256 threads. R4/R9/R10 scaling law: duration ∝ per-block
// LDS work (per-CU LDS unit is the serialized resource). Both mms use 2x2
// register tiling (1 read/FMA) with LDS layouts chosen so every read pair
// is 2 contiguous doubles (b128-eligible):
//   A1 = EJ^T, A2 = El^T (transposed at load; stride-2-bank writes = free),
//   A3 = C^T after mm1 (so mm2's C[c][kk] pairs are contiguous).
// Numerics per output element identical to R4 (same FMA order per acc).
// bx<28: lower-tri trailing tile (I>=J), mirror via LDS transpose.
// bx>=28: col/row panel T (+pivot for T==0).
__global__ void __launch_bounds__(256) k_step(
    const double* __restrict__ Ssrc, double* __restrict__ Sdst,
    const double* __restrict__ PgS, double* __restrict__ PgD, int k)
{
    __shared__ double Pl[32][33], A1[32][33], A2[32][33], A3[32][33];
    int bx = blockIdx.x, mat = blockIdx.y;
    const double* S = Ssrc + (size_t)mat*65536;
    double* D = Sdst + (size_t)mat*65536;
    const double* Pp = PgS + (size_t)mat*1024;
    int tid = threadIdx.x;
    int r0 = 2*(tid >> 4), c0 = 2*(tid & 15);
    int Kb = k*32;
    if (bx < 28){
        int I = 0, b = bx;
        while (b >= I+1){ b -= I+1; I++; }
        int J = b;
        int GI = ((I < k) ? I : I + 1) * 32;
        int GJ = ((J < k) ? J : J + 1) * 32;
        // register-stage global loads (12 tile elems + 4 acc inits in flight)
        double rP[4], rE[4], rEJ[4];
        #pragma unroll
        for (int l = 0; l < 4; l++){
            int e = tid + l*256; int r = e >> 5, c = e & 31;
            rP[l]  = Pp[e];
            rE[l]  = S[(size_t)(GI + r)*N + Kb + c];
            rEJ[l] = S[(size_t)(GJ + r)*N + Kb + c];
        }
        double a00 = S[(size_t)(GI+r0)*N + GJ+c0];
        double a01 = S[(size_t)(GI+r0)*N + GJ+c0+1];
        double a10 = S[(size_t)(GI+r0+1)*N + GJ+c0];
        double a11 = S[(size_t)(GI+r0+1)*N + GJ+c0+1];
        #pragma unroll
        for (int l = 0; l < 4; l++){
            int e = tid + l*256; int r = e >> 5, c = e & 31;
            Pl[r][c] = rP[l];     // row-major
            A2[c][r] = rE[l];     // El^T
            A1[c][r] = rEJ[l];    // EJ^T
        }
        __syncthreads();
        // mm1: C[r][c] = sum_kk EJ[r][kk]*Pl[kk][c], 2x2 tile, store C^T in A3
        {
            double s00=0, s01=0, s10=0, s11=0;
            #pragma unroll
            for (int kk = 0; kk < 32; kk++){
                double x0 = A1[kk][r0], x1 = A1[kk][r0+1];     // EJ[r0..][kk]
                double y0 = Pl[kk][c0], y1 = Pl[kk][c0+1];
                s00 += x0*y0; s01 += x0*y1;
                s10 += x1*y0; s11 += x1*y1;
            }
            A3[c0  ][r0  ] = s00;  A3[c0+1][r0  ] = s01;
            A3[c0  ][r0+1] = s10;  A3[c0+1][r0+1] = s11;
        }
        __syncthreads();
        // mm2: a(r,c) -= sum_kk El[r][kk]*C[c][kk]; El^T in A2, C^T in A3
        #pragma unroll
        for (int kk = 0; kk < 32; kk++){
            double x0 = A2[kk][r0], x1 = A2[kk][r0+1];         // El[r0..][kk]
            double b0 = A3[kk][c0], b1 = A3[kk][c0+1];         // C[c0..][kk]
            a00 -= x0*b0; a01 -= x0*b1;
            a10 -= x1*b0; a11 -= x1*b1;
        }
        double* Dp = D + (size_t)(GI + r0)*N + GJ + c0;
        Dp[0]   = a00; Dp[1]   = a01;
        Dp[N]   = a10; Dp[N+1] = a11;
        if (I != J){
            // mirror: D(GJ,GI) = D(GI,GJ)^T via LDS (A3 dead, reuse normal layout)
            __syncthreads();
            A3[r0][c0]   = a00; A3[r0][c0+1]   = a01;
            A3[r0+1][c0] = a10; A3[r0+1][c0+1] = a11;
            __syncthreads();
            #pragma unroll
            for (int l = 0; l < 4; l++){
                int e = tid + l*256; int r = e >> 5, c = e & 31;
                D[(size_t)(GJ + r)*N + GI + c] = A3[c][r];
            }
        } else if (I == k && k < 7){
            // fold next pivot sweep: this block produced dst tile (k+1,k+1)
            __syncthreads();
            A1[r0][c0]   = a00; A1[r0][c0+1]   = a01;   // A1 dead, normal layout
            A1[r0+1][c0] = a10; A1[r0+1][c0+1] = a11;
            __syncthreads();
            sweep32(A1, tid);
            __syncthreads();
            double* Pd = PgD + (size_t)mat*1024;
            #pragma unroll
            for (int l = 0; l < 4; l++){
                int e = tid + l*256; Pd[e] = A1[e>>5][e&31];
            }
        }
    } else {
        int T = bx - 28;
        int GT = ((T < k) ? T : T + 1) * 32;
        double rP[4], rE[4];
        #pragma unroll
        for (int l = 0; l < 4; l++){
            int e = tid + l*256; int r = e >> 5, c = e & 31;
            rP[l] = Pp[e];
            rE[l] = S[(size_t)(GT + r)*N + Kb + c];
        }
        #pragma unroll
        for (int l = 0; l < 4; l++){
            int e = tid + l*256; int r = e >> 5, c = e & 31;
            Pl[r][c] = rP[l];     // row-major
            A2[c][r] = rE[l];     // E^T
        }
        __syncthreads();
        // C[r][c] = sum_kk E[r][kk]*Pl[kk][c], 2x2 tile, store normal in A3
        {
            double s00=0, s01=0, s10=0, s11=0;
            #pragma unroll
            for (int kk = 0; kk < 32; kk++){
                double x0 = A2[kk][r0], x1 = A2[kk][r0+1];
                double y0 = Pl[kk][c0], y1 = Pl[kk][c0+1];
                s00 += x0*y0; s01 += x0*y1;
                s10 += x1*y0; s11 += x1*y1;
            }
            A3[r0  ][c0  ] = s00;  A3[r0  ][c0+1] = s01;
            A3[r0+1][c0  ] = s10;  A3[r0+1][c0+1] = s11;
        }
        __syncthreads();
        #pragma unroll
        for (int l = 0; l < 4; l++){
            int e = tid + l*256; int r = e >> 5, c = e & 31;
            D[(size_t)(GT + r)*N + Kb + c] = A3[r][c];          // col block
        }
        #pragma unroll
        for (int l = 0; l < 4; l++){
            int e = tid + l*256; int cc = e >> 5, rr = e & 31;
            D[(size_t)(Kb + cc)*N + GT + rr] = A3[rr][cc];      // row block = C^T
        }
        if (T == 0){
            #pragma unroll
            for (int l = 0; l < 4; l++){
                int e = tid + l*256; int i = e >> 5, j = e & 31;
                D[(size_t)(Kb + i)*N + Kb + j] = -Pl[i][j];     // pivot block
            }
        }
    }
}

// ------ X[s] = G[s]*B[s] in f64 (G = -Sfin) ------
__global__ void k_x(const double* __restrict__ Sfin, const double* __restrict__ Bmat,
                    float* __restrict__ Xm){
    int s = blockIdx.z;
    const double* Sp = Sfin + (size_t)s*N*N;
    const double* Bp = Bmat + (size_t)s*N*N;
    float* Xp = Xm + (size_t)s*N*N;
    __shared__ double Gs[32][33], Bs[32][33];
    int tx = threadIdx.x, ty = threadIdx.y;
    int tid = ty*16 + tx;
    int bj = blockIdx.y*32, bi = blockIdx.x*32;
    double a00=0, a01=0, a10=0, a11=0;
    for (int kc = 0; kc < N; kc += 32){
        __syncthreads();
        #pragma unroll
        for (int l = 0; l < 4; l++){
            int e = tid + l*256; int r = e >> 5, c = e & 31;
            Gs[r][c] = -Sp[(size_t)(bj+r)*N + kc + c];
            Bs[r][c] = Bp[(size_t)(kc+r)*N + bi + c];
        }
        __syncthreads();
        #pragma unroll
        for (int k = 0; k < 32; k++){
            double x0 = Gs[2*ty][k], x1 = Gs[2*ty+1][k];
            double y0 = Bs[k][2*tx], y1 = Bs[k][2*tx+1];
            a00 += x0*y0; a01 += x0*y1;
            a10 += x1*y0; a11 += x1*y1;
        }
    }
    Xp[(bj+2*ty  )*N + bi+2*tx  ] = (float)a00;
    Xp[(bj+2*ty  )*N + bi+2*tx+1] = (float)a01;
    Xp[(bj+2*ty+1)*N + bi+2*tx  ] = (float)a10;
    Xp[(bj+2*ty+1)*N + bi+2*tx+1] = (float)a11;
}

// ---- b<64: relu(avg over sigma of Xm) column sums -> dsum (f64 atomics).
// ---- b in 64..67: numerator solve rnum[s] = Gnum*b (coalesced via symmetry).
__global__ void k_red(const float* __restrict__ Xm, const double* __restrict__ Sfin,
                      const double* __restrict__ bpart, double* __restrict__ dsum,
                      float* __restrict__ rnum){
    __shared__ double cp[32][33];
    __shared__ double bsh[256];
    int b = blockIdx.x, tid = threadIdx.x;
    if (b < 64){
        int bj = (b >> 3)*32, bi = (b & 7)*32;
        #pragma unroll
        for (int l = 0; l < 4; l++){
            int e = tid + l*256; int r = e >> 5, c = e & 31;
            int o = (bj + r)*N + bi + c;
            float x = Xm[0*N*N + o] + Xm[1*N*N + o] + Xm[2*N*N + o] + Xm[3*N*N + o];
            cp[r][c] = (double)fmaxf(0.25f*x, 0.f);
        }
        __syncthreads();
        if (tid < 32){
            double ssum = 0;
            #pragma unroll
            for (int r = 0; r < 32; r++) ssum += cp[r][tid];
            atomicAdd(&dsum[bi + tid], ssum);
        }
    } else {
        int s = b - 64, j = tid;
        const double* Sn = Sfin + (size_t)(4+s)*N*N;
        const double* bp = bpart + (size_t)s*N*16;
        double acc = 0;
        #pragma unroll
        for (int t = 0; t < 16; t++) acc += bp[j*16 + t];
        bsh[j] = acc;
        __syncthreads();
        double y = 0;
        for (int k = 0; k < N; k++) y -= Sn[(size_t)k*N + j] * bsh[k];
        rnum[s*N + j] = (float)y;
    }
}

// ---------------- final loss ----------------
__global__ void k_loss2(const double* __restrict__ dsum, const float* __restrict__ rnum,
                        float* __restrict__ out){
    __shared__ double red[256];
    int i = threadIdx.x;
    double denum = dsum[i] + (double)N * 1.0e-3;
    float ravg = 0.25f*(rnum[0*N+i] + rnum[1*N+i] + rnum[2*N+i] + rnum[3*N+i]);
    double rn = (double)fmaxf(ravg, 0.f) + 1.0e-3;
    red[i] = log(rn) + log(denum);
    __syncthreads();
    for (int st = 128; st > 0; st >>= 1){
        if (i < st) red[i] += red[i + st];
        __syncthreads();
    }
    if (i == 0) out[0] = (float)red[0];
}

extern "C" void kernel_launch(void* const* d_in, const int* in_sizes, int n_in,
                              void* d_out, int out_size, void* d_ws, size_t ws_size,
                              hipStream_t stream) {
    (void)in_sizes; (void)n_in; (void)out_size; (void)ws_size;
    const float* z1 = (const float*)d_in[0];
    const float* z2 = (const float*)d_in[1];
    const int*   p1 = (const int*)d_in[2];
    const int*   p2 = (const int*)d_in[3];
    float* out = (float*)d_out;

    char* w = (char*)d_ws;
    size_t o = 0;
    auto carve = [&](size_t bytes) -> char* {
        char* p = w + o;
        o += (bytes + 255) & ~(size_t)255;
        return p;
    };
    double* bpart = (double*)carve((size_t)4*N*16*sizeof(double));
    double* dsum  = (double*)carve((size_t)N*sizeof(double));
    float*  M4    = (float*) carve((size_t)4*N*N*sizeof(float));
    float*  U4    = (float*) carve((size_t)4*N*N*sizeof(float));
    double* Bmat  = (double*)carve((size_t)4*N*N*sizeof(double));
    float*  Xm    = (float*) carve((size_t)4*N*N*sizeof(float));
    float*  rnum  = (float*) carve((size_t)4*N*sizeof(float));
    double* S0    = (double*)carve((size_t)8*N*N*sizeof(double));  // ping
    double* S1    = (double*)carve((size_t)8*N*N*sizeof(double));  // pong
    double* Pg0   = (double*)carve((size_t)8*32*32*sizeof(double));
    double* Pg1   = (double*)carve((size_t)8*32*32*sizeof(double));

    k_dist<<<dim3(16,16,5), dim3(16,16), 0, stream>>>(z1, z2, p1, p2,
                                                      S0, M4, U4, bpart);
    k_gemm_nt<<<dim3(8,8,5), dim3(16,16), 0, stream>>>(M4, U4, Bmat, S0, Pg0, dsum);
    for (int k = 0; k < 8; k++){
        double* src = (k & 1) ? S1 : S0;
        double* dst = (k & 1) ? S0 : S1;
        double* ps  = (k & 1) ? Pg1 : Pg0;
        double* pd  = (k & 1) ? Pg0 : Pg1;
        k_step<<<dim3(35,8), dim3(256), 0, stream>>>(src, dst, ps, pd, k);
    }
    // after k=7 (odd): final swept matrices in S0
    k_x<<<dim3(8,8,4), dim3(16,16), 0, stream>>>(S0, Bmat, Xm);
    k_red<<<dim3(68), dim3(256), 0, stream>>>(Xm, S0, bpart, dsum, rnum);
    k_loss2<<<dim3(1), dim3(256), 0, stream>>>(dsum, rnum, out);
}